// Round 1
// baseline (1298.949 us; speedup 1.0000x reference)
//
#include <hip/hip_runtime.h>

// LSTM: B=4096, T=2048, I=4, H=3, gate order i,f,g,o (rows 0..11 of 4H)
// inputs: 0=input_seq [B,T,4] f32, 1=W_ih [12,4], 2=W_hh [12,3],
//         3=b_ih [12], 4=b_hh [12], 5=length [B] int32
// output: [B,T,3] f32, zeroed where t >= length[b]

#define BB 4096
#define TT 2048

// sigma(z) = rcp(1 + exp2(-L*z))        (sigma rows pre-scaled by -L)
// tanh(z)  = 1 - 2*rcp(1 + exp2(2L*z))  (tanh rows pre-scaled by +2L)
#define LOG2E 1.4426950408889634f

__global__ __launch_bounds__(64) void lstm_seq(
    const float* __restrict__ x, const float* __restrict__ Wih,
    const float* __restrict__ Whh, const float* __restrict__ bih,
    const float* __restrict__ bhh, const int* __restrict__ len,
    float* __restrict__ out)
{
    const int b = blockIdx.x * 64 + threadIdx.x;

    // Load + pre-scale weights into registers (wave-uniform values).
    float wih[12][4], whh[12][3], bb[12];
    #pragma unroll
    for (int r = 0; r < 12; ++r) {
        const float s = (r >= 6 && r < 9) ? (2.f * LOG2E) : (-LOG2E);
        #pragma unroll
        for (int i = 0; i < 4; ++i) wih[r][i] = Wih[r * 4 + i] * s;
        #pragma unroll
        for (int j = 0; j < 3; ++j) whh[r][j] = Whh[r * 3 + j] * s;
        bb[r] = (bih[r] + bhh[r]) * s;
    }

    const int mylen = len[b];
    int wmax = mylen;
    #pragma unroll
    for (int off = 1; off < 64; off <<= 1)
        wmax = max(wmax, __shfl_xor(wmax, off));

    float h0 = 0.f, h1 = 0.f, h2 = 0.f;
    float c0 = 0.f, c1 = 0.f, c2 = 0.f;
    const float4* __restrict__ xrow = ((const float4*)x) + (size_t)b * TT;
    float* __restrict__ orow = out + (size_t)b * TT * 3;

    for (int t = 0; t < wmax; ++t) {
        const float4 xv = xrow[t];
        float a[12];
        #pragma unroll
        for (int r = 0; r < 12; ++r) {
            float v = bb[r];
            v = fmaf(wih[r][0], xv.x, v);
            v = fmaf(wih[r][1], xv.y, v);
            v = fmaf(wih[r][2], xv.z, v);
            v = fmaf(wih[r][3], xv.w, v);
            v = fmaf(whh[r][0], h0, v);
            v = fmaf(whh[r][1], h1, v);
            v = fmaf(whh[r][2], h2, v);
            a[r] = v;
        }
        float nh[3], nc[3];
        const float cc[3] = {c0, c1, c2};
        #pragma unroll
        for (int k = 0; k < 3; ++k) {
            const float ig = __builtin_amdgcn_rcpf(1.f + __builtin_amdgcn_exp2f(a[k]));
            const float fg = __builtin_amdgcn_rcpf(1.f + __builtin_amdgcn_exp2f(a[3 + k]));
            const float gg = fmaf(-2.f, __builtin_amdgcn_rcpf(1.f + __builtin_amdgcn_exp2f(a[6 + k])), 1.f);
            const float og = __builtin_amdgcn_rcpf(1.f + __builtin_amdgcn_exp2f(a[9 + k]));
            const float cn = fmaf(fg, cc[k], ig * gg);
            const float tc = fmaf(-2.f, __builtin_amdgcn_rcpf(1.f + __builtin_amdgcn_exp2f(cn * (2.f * LOG2E))), 1.f);
            nc[k] = cn;
            nh[k] = og * tc;
        }
        c0 = nc[0]; c1 = nc[1]; c2 = nc[2];
        h0 = nh[0]; h1 = nh[1]; h2 = nh[2];
        if (t < mylen) {
            orow[t * 3 + 0] = h0;
            orow[t * 3 + 1] = h1;
            orow[t * 3 + 2] = h2;
        }
    }
}

// Coalesced zero-fill of the invalid suffix (t >= length[b]).
__global__ __launch_bounds__(256) void zero_tail(
    const int* __restrict__ len, float* __restrict__ out)
{
    const size_t idx = (size_t)blockIdx.x * 256 + threadIdx.x;  // float4 index
    const size_t v = idx * 4;                                   // float index
    const int row = (int)(v / (TT * 3));                        // batch b
    const int off = (int)(v - (size_t)row * (TT * 3));          // offset in row
    const int len3 = len[row] * 3;
    if (off >= len3) {
        ((float4*)out)[idx] = make_float4(0.f, 0.f, 0.f, 0.f);
    } else if (off + 4 > len3) {
        #pragma unroll
        for (int cmp = 0; cmp < 4; ++cmp)
            if (off + cmp >= len3) out[v + cmp] = 0.f;
    }
}

extern "C" void kernel_launch(void* const* d_in, const int* in_sizes, int n_in,
                              void* d_out, int out_size, void* d_ws, size_t ws_size,
                              hipStream_t stream) {
    const float* x    = (const float*)d_in[0];
    const float* Wih  = (const float*)d_in[1];
    const float* Whh  = (const float*)d_in[2];
    const float* bih  = (const float*)d_in[3];
    const float* bhh  = (const float*)d_in[4];
    const int*   len  = (const int*)d_in[5];
    float* out = (float*)d_out;

    lstm_seq<<<BB / 64, 64, 0, stream>>>(x, Wih, Whh, bih, bhh, len, out);
    const int nvec4 = BB * TT * 3 / 4;            // 6291456
    zero_tail<<<nvec4 / 256, 256, 0, stream>>>(len, out);
}

// Round 2
// 516.459 us; speedup vs baseline: 2.5151x; 2.5151x over previous
//
#include <hip/hip_runtime.h>

// LSTM: B=4096, T=2048, I=4, H=3, gates i,f,g,o (rows 0..11 of 4H)
// R2: 4 lanes per sequence (lane = hidden unit; lane 3 duplicates unit 2),
//     DPP quad_perm h-broadcast, 8-deep ping-pong x prefetch.

#define BB 4096
#define TT 2048
#define LOG2E 1.4426950408889634f

template<int CTRL>
__device__ __forceinline__ float qperm(float v) {
    int i = __builtin_amdgcn_update_dpp(0, __float_as_int(v), CTRL, 0xF, 0xF, true);
    return __int_as_float(i);
}

__global__ __launch_bounds__(64, 1) void lstm_seq(
    const float* __restrict__ x, const float* __restrict__ Wih,
    const float* __restrict__ Whh, const float* __restrict__ bih,
    const float* __restrict__ bhh, const int* __restrict__ len,
    float* __restrict__ out)
{
    const int lane = threadIdx.x & 63;
    const int sub  = lane & 3;            // gate-lane within group
    const int grp  = lane >> 2;           // 0..15
    const int b    = blockIdx.x * 16 + grp;
    const int k    = (sub < 3) ? sub : 2; // my hidden unit (lane 3 dups unit 2)

    // Per-lane pre-scaled weights. Rows r = g*3 + k, g in {i,f,g,o}.
    // sigma rows scaled by -log2e (sig(z)=rcp(1+exp2(-L z)));
    // tanh rows by +2 log2e   (tanh(z)=1-2 rcp(1+exp2(2L z))).
    float wx[4][4], wh[4][4], bg[4];
    #pragma unroll
    for (int g = 0; g < 4; ++g) {
        const int r = g * 3 + k;
        const float s = (g == 2) ? (2.f * LOG2E) : (-LOG2E);
        #pragma unroll
        for (int i = 0; i < 4; ++i) wx[g][i] = Wih[r * 4 + i] * s;
        #pragma unroll
        for (int sl = 0; sl < 4; ++sl) {
            const int src = sub ^ sl;     // which lane's h lands in slot sl
            wh[g][sl] = (src < 3) ? Whh[r * 3 + src] * s : 0.f;
        }
        bg[g] = (bih[r] + bhh[r]) * s;
    }

    const int mylen = len[b];
    int wmax = mylen;
    #pragma unroll
    for (int off = 1; off < 64; off <<= 1)
        wmax = max(wmax, __shfl_xor(wmax, off));
    wmax = (wmax + 15) & ~15;

    float h[4] = {0.f, 0.f, 0.f, 0.f};    // slot sl holds h of lane sub^sl
    float c = 0.f;
    const float4* __restrict__ xrow = ((const float4*)x) + (size_t)b * TT;
    float* __restrict__ orow = out + (size_t)b * TT * 3;

    float4 bufA[8], bufB[8];
    #pragma unroll
    for (int u = 0; u < 8; ++u) bufA[u] = xrow[u];

    auto step = [&](const float4 xv, const int t) {
        float a[4];
        #pragma unroll
        for (int g = 0; g < 4; ++g) {
            float v = bg[g];
            v = fmaf(wx[g][0], xv.x, v);
            v = fmaf(wx[g][1], xv.y, v);
            v = fmaf(wx[g][2], xv.z, v);
            v = fmaf(wx[g][3], xv.w, v);
            v = fmaf(wh[g][0], h[0], v);
            v = fmaf(wh[g][1], h[1], v);
            v = fmaf(wh[g][2], h[2], v);
            v = fmaf(wh[g][3], h[3], v);
            a[g] = v;
        }
        const float ig = __builtin_amdgcn_rcpf(1.f + __builtin_amdgcn_exp2f(a[0]));
        const float fg = __builtin_amdgcn_rcpf(1.f + __builtin_amdgcn_exp2f(a[1]));
        const float gg = fmaf(-2.f, __builtin_amdgcn_rcpf(1.f + __builtin_amdgcn_exp2f(a[2])), 1.f);
        const float og = __builtin_amdgcn_rcpf(1.f + __builtin_amdgcn_exp2f(a[3]));
        c = fmaf(fg, c, ig * gg);
        const float tc = fmaf(-2.f, __builtin_amdgcn_rcpf(1.f + __builtin_amdgcn_exp2f(c * (2.f * LOG2E))), 1.f);
        const float myh = og * tc;
        h[0] = myh;
        h[1] = qperm<0xB1>(myh);  // xor 1
        h[2] = qperm<0x4E>(myh);  // xor 2
        h[3] = qperm<0x1B>(myh);  // xor 3
        if (sub < 3 && t < mylen) orow[t * 3 + sub] = myh;
    };

    for (int tb = 0; tb < wmax; tb += 16) {
        #pragma unroll
        for (int u = 0; u < 8; ++u) {
            const int tn = tb + 8 + u;
            bufB[u] = xrow[tn < TT ? tn : TT - 1];
        }
        #pragma unroll
        for (int u = 0; u < 8; ++u) step(bufA[u], tb + u);
        #pragma unroll
        for (int u = 0; u < 8; ++u) {
            const int tn = tb + 16 + u;
            bufA[u] = xrow[tn < TT ? tn : TT - 1];
        }
        #pragma unroll
        for (int u = 0; u < 8; ++u) step(bufB[u], tb + 8 + u);
    }
}

// Coalesced zero-fill of the invalid suffix (t >= length[b]).
__global__ __launch_bounds__(256) void zero_tail(
    const int* __restrict__ len, float* __restrict__ out)
{
    const size_t idx = (size_t)blockIdx.x * 256 + threadIdx.x;  // float4 index
    const size_t v = idx * 4;                                   // float index
    const int row = (int)(v / (TT * 3));                        // batch b
    const int off = (int)(v - (size_t)row * (TT * 3));          // offset in row
    const int len3 = len[row] * 3;
    if (off >= len3) {
        ((float4*)out)[idx] = make_float4(0.f, 0.f, 0.f, 0.f);
    } else if (off + 4 > len3) {
        #pragma unroll
        for (int cmp = 0; cmp < 4; ++cmp)
            if (off + cmp >= len3) out[v + cmp] = 0.f;
    }
}

extern "C" void kernel_launch(void* const* d_in, const int* in_sizes, int n_in,
                              void* d_out, int out_size, void* d_ws, size_t ws_size,
                              hipStream_t stream) {
    const float* x    = (const float*)d_in[0];
    const float* Wih  = (const float*)d_in[1];
    const float* Whh  = (const float*)d_in[2];
    const float* bih  = (const float*)d_in[3];
    const float* bhh  = (const float*)d_in[4];
    const int*   lenp = (const int*)d_in[5];
    float* out = (float*)d_out;

    lstm_seq<<<BB / 16, 64, 0, stream>>>(x, Wih, Whh, bih, bhh, lenp, out);
    const int nvec4 = BB * TT * 3 / 4;  // 6291456
    zero_tail<<<nvec4 / 256, 256, 0, stream>>>(lenp, out);
}

// Round 3
// 434.584 us; speedup vs baseline: 2.9889x; 1.1884x over previous
//
#include <hip/hip_runtime.h>

// LSTM: B=4096, T=2048, I=4, H=3, gates i,f,g,o (W rows r = g*3 + u)
// R3: 16 lanes per sequence. quad q = unit (q==3 dups unit 2, never consumed),
//     lane-in-quad s = gate. 1 activation per lane per step (4 trans vs 10).
//     Gate broadcast: quad_perm DPP. h gather: ds_swizzle xor 4/8/12 with
//     zero-weight for the dup quad. Tail zeroing fused (no second kernel).

#define BB 4096
#define TT 2048
#define L2E 1.4426950408889634f

template<int CTRL>
__device__ __forceinline__ float qperm(float v) {
    return __int_as_float(
        __builtin_amdgcn_update_dpp(0, __float_as_int(v), CTRL, 0xF, 0xF, true));
}
template<int PAT>
__device__ __forceinline__ float swz(float v) {
    return __int_as_float(__builtin_amdgcn_ds_swizzle(__float_as_int(v), PAT));
}

__global__ __launch_bounds__(64, 1) void lstm_seq(
    const float* __restrict__ x, const float* __restrict__ Wih,
    const float* __restrict__ Whh, const float* __restrict__ bih,
    const float* __restrict__ bhh, const int* __restrict__ len,
    float* __restrict__ out)
{
    const int lane  = threadIdx.x & 63;
    const int s     = lane & 3;          // gate: 0=i,1=f,2=g,3=o
    const int q     = (lane >> 2) & 3;   // quad = unit (3 = dup of unit 2)
    const int row16 = lane >> 4;         // sequence within wave (4 per wave)
    const int b     = blockIdx.x * 4 + row16;
    const int u     = (q < 3) ? q : 2;
    const int wrow  = s * 3 + u;

    // Activation via r = rcp(1+exp2(a*scale)):
    //   sigmoid (s!=2): scale=-log2e, act = r
    //   tanh    (s==2): scale=+2log2e, act = 1 - 2r
    const float scale = (s == 2) ? (2.f * L2E) : (-L2E);
    const float Aa = (s == 2) ? 1.f : 0.f;
    const float Bb = (s == 2) ? -2.f : 1.f;

    const float xw0 = Wih[wrow * 4 + 0] * scale;
    const float xw1 = Wih[wrow * 4 + 1] * scale;
    const float xw2 = Wih[wrow * 4 + 2] * scale;
    const float xw3 = Wih[wrow * 4 + 3] * scale;
    const float bias = (bih[wrow] + bhh[wrow]) * scale;

    // h slot j arrives from lane^(4j) i.e. quad q^j; zero the dup-quad slot.
    float wh[4];
    #pragma unroll
    for (int j = 0; j < 4; ++j) {
        const int srcq = q ^ j;
        wh[j] = (srcq == 3) ? 0.f : Whh[wrow * 3 + srcq] * scale;
    }

    const int mylen = len[b];
    int wmax = mylen;
    #pragma unroll
    for (int off = 1; off < 64; off <<= 1)
        wmax = max(wmax, __shfl_xor(wmax, off));
    const int Tloop = (wmax + 7) & ~7;

    float hs0 = 0.f, hs1 = 0.f, hs2 = 0.f, hs3 = 0.f, c = 0.f;
    const float4* __restrict__ xrow = ((const float4*)x) + (size_t)b * TT;
    float* __restrict__ orow = out + (size_t)b * (TT * 3);
    const bool writer = (s == 0) && (q < 3);

    float4 buf[8];
    float xacc[8];
    #pragma unroll
    for (int uu = 0; uu < 8; ++uu) buf[uu] = xrow[uu];

    for (int tb = 0; tb < Tloop; tb += 8) {
        #pragma unroll
        for (int uu = 0; uu < 8; ++uu) {
            const float4 xv = buf[uu];
            xacc[uu] = fmaf(xw3, xv.w, fmaf(xw2, xv.z,
                       fmaf(xw1, xv.y, fmaf(xw0, xv.x, bias))));
        }
        #pragma unroll
        for (int uu = 0; uu < 8; ++uu) {
            const int tn = tb + 8 + uu;
            buf[uu] = xrow[tn < TT ? tn : 0];
        }
        #pragma unroll
        for (int uu = 0; uu < 8; ++uu) {
            const int t = tb + uu;
            const float a = fmaf(wh[0], hs0, fmaf(wh[1], hs1,
                            fmaf(wh[2], hs2, fmaf(wh[3], hs3, xacc[uu]))));
            const float r = __builtin_amdgcn_rcpf(1.f + __builtin_amdgcn_exp2f(a));
            const float act = fmaf(Bb, r, Aa);
            const float gi = qperm<0x00>(act);   // lane 0 of quad: gate i
            const float gf = qperm<0x55>(act);   // gate f
            const float gg = qperm<0xAA>(act);   // gate g (tanh)
            const float go = qperm<0xFF>(act);   // gate o
            c = fmaf(gf, c, gi * gg);
            const float tc = fmaf(-2.f,
                __builtin_amdgcn_rcpf(1.f + __builtin_amdgcn_exp2f(c * (2.f * L2E))), 1.f);
            const float myh = go * tc;
            hs0 = myh;
            hs1 = swz<0x101F>(myh);   // lane ^ 4
            hs2 = swz<0x201F>(myh);   // lane ^ 8
            hs3 = swz<0x301F>(myh);   // lane ^ 12
            if (writer) orow[t * 3 + q] = (t < mylen) ? myh : 0.f;
        }
    }

    // Zero the remaining tail t in [Tloop, TT) for this wave's 4 rows.
    const int start4 = Tloop * 3 / 4;          // multiple of 6, 16B-aligned
    #pragma unroll
    for (int rr = 0; rr < 4; ++rr) {
        float4* __restrict__ o4 = (float4*)(out + ((size_t)(blockIdx.x * 4 + rr)) * (TT * 3));
        for (int idx = start4 + lane; idx < TT * 3 / 4; idx += 64)
            o4[idx] = make_float4(0.f, 0.f, 0.f, 0.f);
    }
}

extern "C" void kernel_launch(void* const* d_in, const int* in_sizes, int n_in,
                              void* d_out, int out_size, void* d_ws, size_t ws_size,
                              hipStream_t stream) {
    const float* x    = (const float*)d_in[0];
    const float* Wih  = (const float*)d_in[1];
    const float* Whh  = (const float*)d_in[2];
    const float* bih  = (const float*)d_in[3];
    const float* bhh  = (const float*)d_in[4];
    const int*   lenp = (const int*)d_in[5];
    float* out = (float*)d_out;

    lstm_seq<<<BB / 4, 64, 0, stream>>>(x, Wih, Whh, bih, bhh, lenp, out);
}